// Round 1
// baseline (617.343 us; speedup 1.0000x reference)
//
#include <hip/hip_runtime.h>
#include <math.h>

// Spherical harmonics l=0..3, component normalization, of normalized 3-vectors.
// Memory-bound: 96 MB read, 512 MB write. Strategy: 4 vectors per thread so
// every global access is an exact, aligned float4 (12 floats in, 16 floats
// per output-group boundary-aligned out).

__device__ __forceinline__ void compute_sh(float px, float py, float pz,
                                           float* __restrict__ s1,
                                           float* __restrict__ s2,
                                           float* __restrict__ s3) {
    float sn = px * px + py * py + pz * pz;
    // eps==0 path: zero vector -> u = 0 -> all higher-l outputs 0.
    float inv = (sn == 0.0f) ? 0.0f : rsqrtf(sn);
    float vx = px * inv, vy = py * inv, vz = pz * inv;

    const float SQ3 = 1.7320508075688772f;   // sqrt(3)
    const float S15 = 3.872983346207417f;    // sqrt(15)
    const float SQ5 = 2.23606797749979f;     // sqrt(5)
    const float C42_6 = 1.0801234497346435f; // sqrt(42)/6
    const float C168_8 = 1.6201851746019651f;// sqrt(168)/8
    const float S7 = 2.6457513110645907f;    // sqrt(7)

    float x2 = vx * vx, y2 = vy * vy, z2 = vz * vz;
    float x2z2 = x2 + z2;

    s1[0] = SQ3 * vx;
    s1[1] = SQ3 * vy;
    s1[2] = SQ3 * vz;

    float sh2_0 = S15 * vx * vz;
    float sh2_4 = 0.5f * S15 * (z2 - x2);
    s2[0] = sh2_0;
    s2[1] = S15 * vx * vy;
    s2[2] = SQ5 * (y2 - 0.5f * x2z2);
    s2[3] = S15 * vy * vz;
    s2[4] = sh2_4;

    float q = 4.0f * y2 - x2z2;
    s3[0] = C42_6 * (sh2_0 * vz + sh2_4 * vx);
    s3[1] = S7 * sh2_0 * vy;
    s3[2] = C168_8 * q * vx;
    s3[3] = 0.5f * S7 * vy * (2.0f * y2 - 3.0f * x2z2);
    s3[4] = C168_8 * vz * q;
    s3[5] = S7 * sh2_4 * vy;
    s3[6] = C42_6 * (sh2_4 * vz - sh2_0 * vx);
}

__global__ __launch_bounds__(256) void sh_kernel(const float* __restrict__ x,
                                                 float* __restrict__ out,
                                                 long long nvec) {
    long long nvec4 = nvec >> 2;          // full 4-vector chunks
    long long rem = nvec & 3;
    long long t = (long long)blockIdx.x * blockDim.x + threadIdx.x;

    float* out0 = out;                    // N  floats
    float* out1 = out + nvec;             // 3N floats
    float* out2 = out + 4 * nvec;         // 5N floats
    float* out3 = out + 9 * nvec;         // 7N floats

    if (t < nvec4) {
        const float4* xp = (const float4*)x;
        float in[12];
        float4 a = xp[3 * t + 0];
        float4 b = xp[3 * t + 1];
        float4 c = xp[3 * t + 2];
        in[0] = a.x; in[1] = a.y; in[2]  = a.z; in[3]  = a.w;
        in[4] = b.x; in[5] = b.y; in[6]  = b.z; in[7]  = b.w;
        in[8] = c.x; in[9] = c.y; in[10] = c.z; in[11] = c.w;

        float o1[12], o2[20], o3[28];
#pragma unroll
        for (int k = 0; k < 4; ++k) {
            compute_sh(in[3 * k], in[3 * k + 1], in[3 * k + 2],
                       &o1[3 * k], &o2[5 * k], &o3[7 * k]);
        }

        // sh0: 4 consecutive ones
        ((float4*)out0)[t] = make_float4(1.0f, 1.0f, 1.0f, 1.0f);
        // sh1: 12 consecutive floats at 12*t (16B aligned: 48t bytes)
        float4* p1 = (float4*)(out1 + 12 * t);
#pragma unroll
        for (int k = 0; k < 3; ++k)
            p1[k] = make_float4(o1[4 * k], o1[4 * k + 1], o1[4 * k + 2], o1[4 * k + 3]);
        // sh2: 20 floats at 20*t (80t bytes)
        float4* p2 = (float4*)(out2 + 20 * t);
#pragma unroll
        for (int k = 0; k < 5; ++k)
            p2[k] = make_float4(o2[4 * k], o2[4 * k + 1], o2[4 * k + 2], o2[4 * k + 3]);
        // sh3: 28 floats at 28*t (112t bytes)
        float4* p3 = (float4*)(out3 + 28 * t);
#pragma unroll
        for (int k = 0; k < 7; ++k)
            p3[k] = make_float4(o3[4 * k], o3[4 * k + 1], o3[4 * k + 2], o3[4 * k + 3]);
    } else if (t == nvec4 && rem) {
        // scalar tail (not taken for N=8e6, kept for generality)
        for (long long i = nvec4 * 4; i < nvec; ++i) {
            float s1[3], s2[5], s3[7];
            compute_sh(x[3 * i], x[3 * i + 1], x[3 * i + 2], s1, s2, s3);
            out0[i] = 1.0f;
            for (int k = 0; k < 3; ++k) out1[3 * i + k] = s1[k];
            for (int k = 0; k < 5; ++k) out2[5 * i + k] = s2[k];
            for (int k = 0; k < 7; ++k) out3[7 * i + k] = s3[k];
        }
    }
}

extern "C" void kernel_launch(void* const* d_in, const int* in_sizes, int n_in,
                              void* d_out, int out_size, void* d_ws, size_t ws_size,
                              hipStream_t stream) {
    const float* x = (const float*)d_in[0];
    float* out = (float*)d_out;
    long long nvec = (long long)in_sizes[0] / 3;
    long long threads_needed = (nvec >> 2) + ((nvec & 3) ? 1 : 0);
    int block = 256;
    long long grid = (threads_needed + block - 1) / block;
    sh_kernel<<<(dim3)(unsigned)grid, block, 0, stream>>>(x, out, nvec);
}